// Round 1
// baseline (543.172 us; speedup 1.0000x reference)
//
#include <hip/hip_runtime.h>
#include <hip/hip_bf16.h>

// Problem constants (S=2048, B=2, E=2048, H=32, D=64)
#define S_LEN 2048
#define BATCH 2
#define EMB   2048
#define NH    32
#define HD    64
#define M_ROWS (S_LEN * BATCH)   // 4096
#define QKV_N  (3 * EMB)         // 6144

typedef short bf16x8 __attribute__((ext_vector_type(8)));
typedef float f32x4  __attribute__((ext_vector_type(4)));

__device__ __forceinline__ unsigned short f2bf(float f) {
  unsigned int u = __float_as_uint(f);
  u += 0x7fffu + ((u >> 16) & 1u);       // round-to-nearest-even
  return (unsigned short)(u >> 16);
}
__device__ __forceinline__ float bf2f(unsigned short h) {
  return __uint_as_float(((unsigned int)h) << 16);
}
__device__ __forceinline__ void async_copy16(const void* g, void* lds) {
  __builtin_amdgcn_global_load_lds(
      (const __attribute__((address_space(1))) void*)g,
      (__attribute__((address_space(3))) void*)lds, 16, 0, 0);
}

// ---------------- prep kernels ----------------

__global__ __launch_bounds__(256) void cast_to_bf16(
    const float* __restrict__ in, unsigned short* __restrict__ out, int n4) {
  int i = blockIdx.x * 256 + threadIdx.x;
  if (i >= n4) return;
  float4 v = reinterpret_cast<const float4*>(in)[i];
  ushort4 o;
  o.x = f2bf(v.x); o.y = f2bf(v.y); o.z = f2bf(v.z); o.w = f2bf(v.w);
  reinterpret_cast<ushort4*>(out)[i] = o;
}

// in [R][C] f32 -> out [C][R] bf16
__global__ __launch_bounds__(256) void transpose_cast(
    const float* __restrict__ in, unsigned short* __restrict__ out, int R, int C) {
  __shared__ float tile[32][33];
  const int bc = blockIdx.x * 32, br = blockIdx.y * 32;
  const int tx = threadIdx.x & 31, ty = threadIdx.x >> 5;   // ty 0..7
  #pragma unroll
  for (int rr = ty; rr < 32; rr += 8)
    tile[rr][tx] = in[(size_t)(br + rr) * C + bc + tx];
  __syncthreads();
  #pragma unroll
  for (int rr = ty; rr < 32; rr += 8)
    out[(size_t)(bc + rr) * R + br + tx] = f2bf(tile[tx][rr]);
}

// ---------------- QKV GEMM: A[4096,2048]bf16 x Wt[6144,2048]bf16 + bias ----------------
// Scatter epilogue into Q/K/V [B,H,S,D] bf16.

__global__ __launch_bounds__(256) void gemm_qkv(
    const unsigned short* __restrict__ A,
    const unsigned short* __restrict__ Wt,
    const float* __restrict__ bias,
    unsigned short* __restrict__ Qo,
    unsigned short* __restrict__ Ko,
    unsigned short* __restrict__ Vo) {
  __shared__ __align__(16) unsigned short As[128 * 32];
  __shared__ __align__(16) unsigned short Bs[128 * 32];
  const int tid = threadIdx.x;
  const int n0 = blockIdx.x * 128;
  const int m0 = blockIdx.y * 128;
  const int wave = tid >> 6, lane = tid & 63;
  const int wm = (wave >> 1) * 64, wn = (wave & 1) * 64;
  const int lm = lane & 15, lq = lane >> 4;
  const int K = 2048;

  // staging: chunk c -> LDS offset c*16B; row = c>>2, kchunk = c&3
  const int r0 = tid >> 2, kc0 = (tid & 3) * 8;
  const unsigned short* Ar0 = A  + (size_t)(m0 + r0) * K + kc0;
  const unsigned short* Ar1 = Ar0 + (size_t)64 * K;
  const unsigned short* Br0 = Wt + (size_t)(n0 + r0) * K + kc0;
  const unsigned short* Br1 = Br0 + (size_t)64 * K;
  unsigned short* As0 = As + tid * 8;
  unsigned short* As1 = As + (tid + 256) * 8;
  unsigned short* Bs0 = Bs + tid * 8;
  unsigned short* Bs1 = Bs + (tid + 256) * 8;

  f32x4 acc[4][4] = {};

  for (int k0 = 0; k0 < K; k0 += 32) {
    async_copy16(Ar0 + k0, As0);
    async_copy16(Ar1 + k0, As1);
    async_copy16(Br0 + k0, Bs0);
    async_copy16(Br1 + k0, Bs1);
    __syncthreads();
    bf16x8 a[4], b[4];
    #pragma unroll
    for (int i = 0; i < 4; i++)
      a[i] = *reinterpret_cast<const bf16x8*>(As + (wm + i*16 + lm) * 32 + lq*8);
    #pragma unroll
    for (int j = 0; j < 4; j++)
      b[j] = *reinterpret_cast<const bf16x8*>(Bs + (wn + j*16 + lm) * 32 + lq*8);
    #pragma unroll
    for (int i = 0; i < 4; i++)
      #pragma unroll
      for (int j = 0; j < 4; j++)
        acc[i][j] = __builtin_amdgcn_mfma_f32_16x16x32_bf16(a[i], b[j], acc[i][j], 0, 0, 0);
    __syncthreads();
  }

  // epilogue: bias + bf16 + scatter into [B,H,S,D]
  const int which = n0 >> 11;   // 0=q 1=k 2=v, uniform per block (2048 % 128 == 0)
  unsigned short* dst = (which == 0) ? Qo : (which == 1) ? Ko : Vo;
  #pragma unroll
  for (int j = 0; j < 4; j++) {
    const int n = n0 + wn + j*16 + lm;
    const float bv = bias[n];
    const int e = n & (EMB - 1), h = e >> 6, d = e & 63;
    #pragma unroll
    for (int i = 0; i < 4; i++) {
      #pragma unroll
      for (int r = 0; r < 4; r++) {
        const int m = m0 + wm + i*16 + lq*4 + r;           // C-layout row
        const int s = m >> 1, b = m & 1;                   // m = s*B + b
        dst[(((size_t)b * NH + h) * S_LEN + s) * HD + d] = f2bf(acc[i][j][r] + bv);
      }
    }
  }
}

// ---------------- RoPE (GPT-NeoX, full head dim) in-place on Q,K [B,H,S,D] ----------------

__global__ __launch_bounds__(256) void rope_kernel(
    unsigned short* __restrict__ Q, unsigned short* __restrict__ K) {
  const int idx = blockIdx.x * 256 + threadIdx.x;  // bits: d(5) s(11) bh(6)
  const int d  = idx & 31;
  const int s  = (idx >> 5) & (S_LEN - 1);
  const int bh = idx >> 16;
  const float inv_freq = __expf(d * -0.28782313662425575f);  // ln(10000)/32
  const float ang = (float)s * inv_freq;
  float sn, cs;
  __sincosf(ang, &sn, &cs);
  const size_t base = ((size_t)bh * S_LEN + s) * HD + d;
  float q1 = bf2f(Q[base]), q2 = bf2f(Q[base + 32]);
  Q[base]      = f2bf(q1 * cs - q2 * sn);
  Q[base + 32] = f2bf(q2 * cs + q1 * sn);
  float k1 = bf2f(K[base]), k2 = bf2f(K[base + 32]);
  K[base]      = f2bf(k1 * cs - k2 * sn);
  K[base + 32] = f2bf(k2 * cs + k1 * sn);
}

// ---------------- V [B,H,S,D] -> VT [B,H,D,S] ----------------

__global__ __launch_bounds__(256) void transpose_v(
    const unsigned short* __restrict__ V, unsigned short* __restrict__ VT) {
  __shared__ unsigned short t[64][65];
  const int bh = blockIdx.y;
  const int s0 = blockIdx.x * 64;
  const int tx = threadIdx.x & 63, ty = threadIdx.x >> 6;  // ty 0..3
  const unsigned short* src = V + ((size_t)bh * S_LEN + s0) * HD;
  #pragma unroll
  for (int r = ty; r < 64; r += 4)
    t[r][tx] = src[(size_t)r * HD + tx];
  __syncthreads();
  unsigned short* dst = VT + (size_t)bh * HD * S_LEN + s0;
  #pragma unroll
  for (int r = ty; r < 64; r += 4)
    dst[(size_t)r * S_LEN + tx] = t[tx][r];
}

// ---------------- Flash attention (causal), bf16 MFMA, f32 online softmax ----------------
// Block = (head bh, 128 Q rows). 4 independent waves x 32 rows. T-tiles of 64. No barriers.

__global__ __launch_bounds__(256) void attn_kernel(
    const unsigned short* __restrict__ Q,
    const unsigned short* __restrict__ K,
    const unsigned short* __restrict__ VT,
    unsigned short* __restrict__ ctx) {
  const int bh = blockIdx.x;               // b*32+h
  const int q0 = blockIdx.y * 128;
  const int wave = threadIdx.x >> 6, lane = threadIdx.x & 63;
  const int lm = lane & 15, lq = lane >> 4;
  const unsigned short* Qbh = Q  + (size_t)bh * S_LEN * HD;
  const unsigned short* Kbh = K  + (size_t)bh * S_LEN * HD;
  const unsigned short* Vbh = VT + (size_t)bh * HD * S_LEN;

  // P scratch: per-wave 32x64 bf16, rows padded to 72 (16B-aligned rows, conflict shift)
  __shared__ __align__(16) unsigned short Pbuf[4][32][72];

  const int r0 = q0 + wave * 32;

  // Q fragments (A-layout): rows r0+i*16+lm, k = ks*32 + lq*8
  bf16x8 qf[2][2];
  #pragma unroll
  for (int i = 0; i < 2; i++)
    #pragma unroll
    for (int ks = 0; ks < 2; ks++)
      qf[i][ks] = *reinterpret_cast<const bf16x8*>(
          Qbh + (size_t)(r0 + i*16 + lm) * HD + ks*32 + lq*8);

  f32x4 O[2][4] = {};
  float mrow[2][4], lrow[2][4];
  #pragma unroll
  for (int i = 0; i < 2; i++)
    #pragma unroll
    for (int r = 0; r < 4; r++) { mrow[i][r] = -1e30f; lrow[i][r] = 0.0f; }

  const int tmax = r0 + 31;                // wave's last valid key row
  for (int t0 = 0; t0 <= tmax; t0 += 64) {
    // S = Q K^T  (B-frag of K^T is K row-major: contiguous 16B per lane)
    f32x4 sc[2][4] = {};
    #pragma unroll
    for (int ks = 0; ks < 2; ks++) {
      bf16x8 kf[4];
      #pragma unroll
      for (int j = 0; j < 4; j++)
        kf[j] = *reinterpret_cast<const bf16x8*>(
            Kbh + (size_t)(t0 + j*16 + lm) * HD + ks*32 + lq*8);
      #pragma unroll
      for (int i = 0; i < 2; i++)
        #pragma unroll
        for (int j = 0; j < 4; j++)
          sc[i][j] = __builtin_amdgcn_mfma_f32_16x16x32_bf16(qf[i][ks], kf[j], sc[i][j], 0, 0, 0);
    }

    const bool needmask = (t0 + 63 > r0);
    #pragma unroll
    for (int i = 0; i < 2; i++) {
      #pragma unroll
      for (int r = 0; r < 4; r++) {
        const int srow = r0 + i*16 + lq*4 + r;  // C-layout row
        float v[4], mx = -1e30f;
        #pragma unroll
        for (int j = 0; j < 4; j++) {
          float x = sc[i][j][r] * 0.125f;       // 1/sqrt(64)
          if (needmask) {
            const int t = t0 + j*16 + lm;
            x = (t <= srow) ? x : -1e30f;
          }
          v[j] = x;
          mx = fmaxf(mx, x);
        }
        #pragma unroll
        for (int off = 1; off < 16; off <<= 1)
          mx = fmaxf(mx, __shfl_xor(mx, off, 64));
        const float mnew = fmaxf(mrow[i][r], mx);
        const float al = __expf(mrow[i][r] - mnew);
        mrow[i][r] = mnew;
        float sum = 0.0f;
        #pragma unroll
        for (int j = 0; j < 4; j++) {
          const float p = __expf(v[j] - mnew);
          sum += p;
          Pbuf[wave][i*16 + lq*4 + r][j*16 + lm] = f2bf(p);
        }
        #pragma unroll
        for (int off = 1; off < 16; off <<= 1)
          sum += __shfl_xor(sum, off, 64);
        lrow[i][r] = lrow[i][r] * al + sum;
        #pragma unroll
        for (int j = 0; j < 4; j++)
          O[i][j][r] *= al;
      }
    }

    // O += P V   (P via LDS round-trip to A-layout; V^T rows contiguous in t)
    #pragma unroll
    for (int ks = 0; ks < 2; ks++) {
      bf16x8 pf[2], vf[4];
      #pragma unroll
      for (int i = 0; i < 2; i++)
        pf[i] = *reinterpret_cast<const bf16x8*>(&Pbuf[wave][i*16 + lm][ks*32 + lq*8]);
      #pragma unroll
      for (int j = 0; j < 4; j++)
        vf[j] = *reinterpret_cast<const bf16x8*>(
            Vbh + (size_t)(j*16 + lm) * S_LEN + t0 + ks*32 + lq*8);
      #pragma unroll
      for (int i = 0; i < 2; i++)
        #pragma unroll
        for (int j = 0; j < 4; j++)
          O[i][j] = __builtin_amdgcn_mfma_f32_16x16x32_bf16(pf[i], vf[j], O[i][j], 0, 0, 0);
    }
  }

  // epilogue: O/l -> ctx [S,B,E] bf16
  const int b = bh >> 5, h = bh & 31;
  #pragma unroll
  for (int i = 0; i < 2; i++) {
    #pragma unroll
    for (int r = 0; r < 4; r++) {
      const int srow = r0 + i*16 + lq*4 + r;
      const float inv = 1.0f / lrow[i][r];
      #pragma unroll
      for (int j = 0; j < 4; j++) {
        const int d = j*16 + lm;
        ctx[((size_t)srow * BATCH + b) * EMB + h*HD + d] = f2bf(O[i][j][r] * inv);
      }
    }
  }
}

// ---------------- Output GEMM: ctx[4096,2048]bf16 x outWt[2048,2048]bf16 + bias -> f32 ----------------

__global__ __launch_bounds__(256) void gemm_out(
    const unsigned short* __restrict__ A,
    const unsigned short* __restrict__ Wt,
    const float* __restrict__ bias,
    float* __restrict__ out) {
  __shared__ __align__(16) unsigned short As[128 * 32];
  __shared__ __align__(16) unsigned short Bs[128 * 32];
  const int tid = threadIdx.x;
  const int n0 = blockIdx.x * 128;
  const int m0 = blockIdx.y * 128;
  const int wave = tid >> 6, lane = tid & 63;
  const int wm = (wave >> 1) * 64, wn = (wave & 1) * 64;
  const int lm = lane & 15, lq = lane >> 4;
  const int K = 2048;

  const int r0 = tid >> 2, kc0 = (tid & 3) * 8;
  const unsigned short* Ar0 = A  + (size_t)(m0 + r0) * K + kc0;
  const unsigned short* Ar1 = Ar0 + (size_t)64 * K;
  const unsigned short* Br0 = Wt + (size_t)(n0 + r0) * K + kc0;
  const unsigned short* Br1 = Br0 + (size_t)64 * K;
  unsigned short* As0 = As + tid * 8;
  unsigned short* As1 = As + (tid + 256) * 8;
  unsigned short* Bs0 = Bs + tid * 8;
  unsigned short* Bs1 = Bs + (tid + 256) * 8;

  f32x4 acc[4][4] = {};

  for (int k0 = 0; k0 < K; k0 += 32) {
    async_copy16(Ar0 + k0, As0);
    async_copy16(Ar1 + k0, As1);
    async_copy16(Br0 + k0, Bs0);
    async_copy16(Br1 + k0, Bs1);
    __syncthreads();
    bf16x8 a[4], b[4];
    #pragma unroll
    for (int i = 0; i < 4; i++)
      a[i] = *reinterpret_cast<const bf16x8*>(As + (wm + i*16 + lm) * 32 + lq*8);
    #pragma unroll
    for (int j = 0; j < 4; j++)
      b[j] = *reinterpret_cast<const bf16x8*>(Bs + (wn + j*16 + lm) * 32 + lq*8);
    #pragma unroll
    for (int i = 0; i < 4; i++)
      #pragma unroll
      for (int j = 0; j < 4; j++)
        acc[i][j] = __builtin_amdgcn_mfma_f32_16x16x32_bf16(a[i], b[j], acc[i][j], 0, 0, 0);
    __syncthreads();
  }

  #pragma unroll
  for (int j = 0; j < 4; j++) {
    const int n = n0 + wn + j*16 + lm;
    const float bv = bias[n];
    #pragma unroll
    for (int i = 0; i < 4; i++) {
      #pragma unroll
      for (int r = 0; r < 4; r++) {
        const int m = m0 + wm + i*16 + lq*4 + r;
        out[(size_t)m * EMB + n] = acc[i][j][r] + bv;
      }
    }
  }
}

// ---------------- host launcher ----------------

extern "C" void kernel_launch(void* const* d_in, const int* in_sizes, int n_in,
                              void* d_out, int out_size, void* d_ws, size_t ws_size,
                              hipStream_t stream) {
  const float* hidden = (const float*)d_in[0];
  const float* qkv_w  = (const float*)d_in[1];
  const float* qkv_b  = (const float*)d_in[2];
  const float* out_w  = (const float*)d_in[3];
  const float* out_b  = (const float*)d_in[4];
  float* out = (float*)d_out;

  unsigned short* ws = (unsigned short*)d_ws;
  unsigned short* hbf   = ws;                                  // 4096*2048
  unsigned short* qkvwT = hbf   + (size_t)M_ROWS * EMB;        // 6144*2048
  unsigned short* outwT = qkvwT + (size_t)QKV_N * EMB;         // 2048*2048
  unsigned short* Qb    = outwT + (size_t)EMB * EMB;           // 64*2048*64 each
  unsigned short* Kb    = Qb    + (size_t)64 * S_LEN * HD;
  unsigned short* Vb    = Kb    + (size_t)64 * S_LEN * HD;
  unsigned short* VTb   = Vb    + (size_t)64 * S_LEN * HD;
  unsigned short* ctx   = VTb   + (size_t)64 * S_LEN * HD;     // 4096*2048

  // 1. casts / transposes
  cast_to_bf16<<<(M_ROWS * EMB / 4) / 256, 256, 0, stream>>>(hidden, hbf, M_ROWS * EMB / 4);
  transpose_cast<<<dim3(QKV_N / 32, EMB / 32), 256, 0, stream>>>(qkv_w, qkvwT, EMB, QKV_N);
  transpose_cast<<<dim3(EMB / 32, EMB / 32), 256, 0, stream>>>(out_w, outwT, EMB, EMB);

  // 2. fused QKV projection + scatter
  gemm_qkv<<<dim3(QKV_N / 128, M_ROWS / 128), 256, 0, stream>>>(hbf, qkvwT, qkv_b, Qb, Kb, Vb);

  // 3. RoPE on Q,K ; V transpose
  rope_kernel<<<(64 * S_LEN * 32) / 256, 256, 0, stream>>>(Qb, Kb);
  transpose_v<<<dim3(S_LEN / 64, 64), 256, 0, stream>>>(Vb, VTb);

  // 4. causal flash attention
  attn_kernel<<<dim3(64, S_LEN / 128), 256, 0, stream>>>(Qb, Kb, VTb, ctx);

  // 5. output projection
  gemm_out<<<dim3(EMB / 128, M_ROWS / 128), 256, 0, stream>>>(ctx, outwT, out_b, out);
}